// Round 8
// baseline (500.329 us; speedup 1.0000x reference)
//
#include <hip/hip_runtime.h>

// GAT 2-layer on gfx950. Inputs f32 (auto-detected, converted to bf16).
// Round 8: MLP-widened gather — each lane covers 32ch (64B, 4x dwordx4),
// 8 edges in flight per wave (L1) / 16 (L2); dropped redundant csr memset.

typedef __bf16 bf16x8 __attribute__((ext_vector_type(8)));
typedef float f32x4 __attribute__((ext_vector_type(4)));

static void* g_scratch = nullptr;
#define SCRATCH_BYTES ((size_t)160 * 1024 * 1024)

__attribute__((constructor)) static void alloc_scratch_at_load() {
    if (hipMalloc(&g_scratch, SCRATCH_BYTES) != hipSuccess) g_scratch = nullptr;
}

__device__ __forceinline__ float bf2f(unsigned short u) {
    union { unsigned int i; float f; } v;
    v.i = ((unsigned int)u) << 16;
    return v.f;
}
__device__ __forceinline__ unsigned short f2bf(float f) {
    union { float f; unsigned int i; } v;
    v.f = f;
    unsigned int x = v.i;
    return (unsigned short)((x + 0x7fffu + ((x >> 16) & 1u)) >> 16); // RNE
}
__device__ __forceinline__ float fin(float v) {
    return (v == v && fabsf(v) <= 3.0e38f) ? v : 0.f;
}

// ---------------- dtype probe + converts ----------------

__global__ void probe_kernel(const unsigned int* __restrict__ xw, int* __restrict__ flag) {
    int lane = threadIdx.x; // 64 threads
    int cnt = 0;
    for (int i = lane; i < 1024; i += 64) {
        float v = bf2f((unsigned short)(xw[i] & 0xffffu));
        float a = fabsf(v);
        if (a >= 0.0078125f && a < 2.0f) cnt++;
    }
    #pragma unroll
    for (int off = 32; off; off >>= 1) cnt += __shfl_xor(cnt, off);
    if (lane == 0) *flag = (cnt < 512) ? 1 : 0; // 1 => f32 inputs
}

__global__ __launch_bounds__(256) void cvtx_kernel(const void* __restrict__ src,
                                                   unsigned short* __restrict__ dst, int n4,
                                                   const int* __restrict__ flag) {
    int i = blockIdx.x * 256 + threadIdx.x;
    if (i >= n4) return;
    if (*flag) {
        float4 f = ((const float4*)src)[i];
        ushort4 o;
        o.x = f2bf(f.x); o.y = f2bf(f.y); o.z = f2bf(f.z); o.w = f2bf(f.w);
        ((ushort4*)dst)[i] = o;
    } else {
        ((uint2*)dst)[i] = ((const uint2*)src)[i];
    }
}

struct CvtBatch {
    const void* src[8];
    unsigned short* dst[8];
    int n[8];
};

__global__ __launch_bounds__(256) void cvt_batch_kernel(CvtBatch b, const int* __restrict__ flag) {
    int i = blockIdx.x * 256 + threadIdx.x;
    int f = *flag;
    #pragma unroll
    for (int s = 0; s < 8; ++s) {
        if (i < b.n[s]) {
            if (f) b.dst[s][i] = f2bf(((const float*)b.src[s])[i]);
            else   b.dst[s][i] = ((const unsigned short*)b.src[s])[i];
            return;
        }
        i -= b.n[s];
    }
}

__global__ __launch_bounds__(256) void fill_kernel(unsigned short* __restrict__ out, int n,
                                                   float val) {
    int i = blockIdx.x * 256 + threadIdx.x;
    if (i < n) out[i] = f2bf(val);
}

// ---------------- CSR build ----------------

__global__ __launch_bounds__(256) void deg_kernel(const int* __restrict__ ei, int E, int N,
                                                  int* __restrict__ deg) {
    int i = blockIdx.x * 256 + threadIdx.x;
    int total = E + N;
    if (i < total) {
        int dst = (i < E) ? ei[E + i] : (i - E);
        if ((unsigned)dst < (unsigned)N) atomicAdd(&deg[dst], 1);
    }
}

__global__ __launch_bounds__(256) void scan_bsum_kernel(const int* __restrict__ deg,
                                                        int* __restrict__ bsum, int n) {
    int tid = threadIdx.x;
    int i = blockIdx.x * 256 + tid;
    int v = (i < n) ? deg[i] : 0;
    #pragma unroll
    for (int off = 32; off; off >>= 1) v += __shfl_xor(v, off);
    __shared__ int sh[4];
    if ((tid & 63) == 0) sh[tid >> 6] = v;
    __syncthreads();
    if (tid == 0) bsum[blockIdx.x] = sh[0] + sh[1] + sh[2] + sh[3];
}

__global__ __launch_bounds__(256) void scan_scan_kernel(int* __restrict__ bsum, int nb,
                                                        int* __restrict__ total) {
    __shared__ int sh[256];
    int tid = threadIdx.x;
    int v = (tid < nb) ? bsum[tid] : 0;
    sh[tid] = v;
    __syncthreads();
    #pragma unroll
    for (int off = 1; off < 256; off <<= 1) {
        int t = (tid >= off) ? sh[tid - off] : 0;
        __syncthreads();
        sh[tid] += t;
        __syncthreads();
    }
    if (tid < nb) bsum[tid] = sh[tid] - v;
    if (tid == 255) *total = sh[255];
}

__global__ __launch_bounds__(256) void scan_write_kernel(const int* __restrict__ deg,
                                                         const int* __restrict__ bsum,
                                                         int* __restrict__ rowptr,
                                                         int* __restrict__ cursor, int n) {
    __shared__ int sh[256];
    int tid = threadIdx.x;
    int i = blockIdx.x * 256 + tid;
    int v = (i < n) ? deg[i] : 0;
    sh[tid] = v;
    __syncthreads();
    #pragma unroll
    for (int off = 1; off < 256; off <<= 1) {
        int t = (tid >= off) ? sh[tid - off] : 0;
        __syncthreads();
        sh[tid] += t;
        __syncthreads();
    }
    if (i < n) {
        int excl = sh[tid] - v + bsum[blockIdx.x];
        rowptr[i] = excl;
        cursor[i] = excl;
    }
}

__global__ __launch_bounds__(256) void scatter_kernel(const int* __restrict__ ei, int E, int N,
                                                      int* __restrict__ cursor,
                                                      int* __restrict__ csr) {
    int i = blockIdx.x * 256 + threadIdx.x;
    int total = E + N;
    if (i < total) {
        int s, d;
        if (i < E) { s = ei[i]; d = ei[E + i]; }
        else       { s = i - E; d = i - E; }
        if ((unsigned)d >= (unsigned)N) return;
        int pos = atomicAdd(&cursor[d], 1);
        if ((unsigned)pos < (unsigned)total) csr[pos] = s;
    }
}

// ---------------- tiled GEMM: C[M,Nc] = A[M,K] * B[Nc,K]^T ----------------

template <int K, int NTN>
__global__ __launch_bounds__(256) void gemm_tile_kernel(const unsigned short* __restrict__ A,
                                                        const unsigned short* __restrict__ B,
                                                        unsigned short* __restrict__ C, int M) {
    __shared__ __align__(16) unsigned short As[128 * 64];
    __shared__ __align__(16) unsigned short Bs[128 * 64];
    const int Nc = NTN * 128;
    int bx = blockIdx.x;
    int mt = bx / NTN, nt = bx % NTN;
    int row0 = mt * 128, n0 = nt * 128;
    int t = threadIdx.x;
    int lane = t & 63, w = t >> 6;
    int wr = w >> 1, wc = w & 1;
    int r = lane & 15, kq = lane >> 4;

    f32x4 acc[4][4];
    #pragma unroll
    for (int i = 0; i < 4; ++i)
        #pragma unroll
        for (int j = 0; j < 4; ++j) acc[i][j] = (f32x4){0.f, 0.f, 0.f, 0.f};

    for (int k0 = 0; k0 < K; k0 += 64) {
        #pragma unroll
        for (int rr = 0; rr < 4; ++rr) {
            int idx = rr * 256 + t;
            int row = idx >> 3, cg = idx & 7;
            int arow = row0 + row; if (arow >= M) arow = M - 1;
            bf16x8 va = *reinterpret_cast<const bf16x8*>(A + (size_t)arow * K + k0 + cg * 8);
            bf16x8 vb = *reinterpret_cast<const bf16x8*>(B + (size_t)(n0 + row) * K + k0 + cg * 8);
            int pc = ((cg ^ (row & 7)) * 8);
            *reinterpret_cast<bf16x8*>(As + row * 64 + pc) = va;
            *reinterpret_cast<bf16x8*>(Bs + row * 64 + pc) = vb;
        }
        __syncthreads();
        #pragma unroll
        for (int ks = 0; ks < 64; ks += 32) {
            int cg = (ks >> 3) + kq;
            bf16x8 af[4], bfr[4];
            #pragma unroll
            for (int i = 0; i < 4; ++i) {
                int rowA = wr * 64 + i * 16 + r;
                af[i] = *reinterpret_cast<const bf16x8*>(As + rowA * 64 + ((cg ^ (rowA & 7)) * 8));
                int rowB = wc * 64 + i * 16 + r;
                bfr[i] = *reinterpret_cast<const bf16x8*>(Bs + rowB * 64 + ((cg ^ (rowB & 7)) * 8));
            }
            #pragma unroll
            for (int i = 0; i < 4; ++i)
                #pragma unroll
                for (int j = 0; j < 4; ++j)
                    acc[i][j] = __builtin_amdgcn_mfma_f32_16x16x32_bf16(af[i], bfr[j], acc[i][j], 0, 0, 0);
        }
        __syncthreads();
    }

    #pragma unroll
    for (int i = 0; i < 4; ++i) {
        #pragma unroll
        for (int q = 0; q < 4; ++q) {
            int row = row0 + wr * 64 + i * 16 + kq * 4 + q;
            if (row < M) {
                #pragma unroll
                for (int j = 0; j < 4; ++j) {
                    int col = n0 + wc * 64 + j * 16 + r;
                    C[(size_t)row * Nc + col] = f2bf(fin(acc[i][j][q]));
                }
            }
        }
    }
}

// ---------------- per-node attention scores ----------------

template <int CPL> // 4 (256ch) or 2 (128ch)
__global__ __launch_bounds__(256) void escore_kernel(const unsigned short* __restrict__ h,
                                                     const unsigned short* __restrict__ a_src,
                                                     const unsigned short* __restrict__ a_dst,
                                                     float* __restrict__ es,
                                                     float* __restrict__ ed, int n) {
    int w = blockIdx.x * 4 + (threadIdx.x >> 6);
    if (w >= n) return;
    int lane = threadIdx.x & 63;
    const int DOUT = CPL * 64;
    float s1 = 0.f, s2 = 0.f;
    if (CPL == 4) {
        uint2 uh = *(const uint2*)(h + (size_t)w * DOUT + lane * 4);
        uint2 us = *(const uint2*)(a_src + lane * 4);
        uint2 ud = *(const uint2*)(a_dst + lane * 4);
        float h0 = bf2f(uh.x & 0xffff), h1v = bf2f(uh.x >> 16);
        float h2v = bf2f(uh.y & 0xffff), h3 = bf2f(uh.y >> 16);
        s1 = h0 * bf2f(us.x & 0xffff) + h1v * bf2f(us.x >> 16)
           + h2v * bf2f(us.y & 0xffff) + h3 * bf2f(us.y >> 16);
        s2 = h0 * bf2f(ud.x & 0xffff) + h1v * bf2f(ud.x >> 16)
           + h2v * bf2f(ud.y & 0xffff) + h3 * bf2f(ud.y >> 16);
    } else {
        unsigned int uh = *(const unsigned int*)(h + (size_t)w * DOUT + lane * 2);
        unsigned int us = *(const unsigned int*)(a_src + lane * 2);
        unsigned int ud = *(const unsigned int*)(a_dst + lane * 2);
        float h0 = bf2f(uh & 0xffff), h1v = bf2f(uh >> 16);
        s1 = h0 * bf2f(us & 0xffff) + h1v * bf2f(us >> 16);
        s2 = h0 * bf2f(ud & 0xffff) + h1v * bf2f(ud >> 16);
    }
    #pragma unroll
    for (int off = 32; off; off >>= 1) {
        s1 += __shfl_xor(s1, off);
        s2 += __shfl_xor(s2, off);
    }
    if (lane == 0) { es[w] = fin(s1); ed[w] = fin(s2); }
}

// ---------------- per-dst softmax + wide-gather aggregation ----------------
// Each lane covers 32 channels (64 B = 4x dwordx4); LPE = CH/32 lanes per edge;
// EPW = 64/LPE edges in flight per inner iteration.

template <int CH, bool RELU, bool DUAL>
__global__ __launch_bounds__(256) void aggregate_kernel(const unsigned short* __restrict__ h,
                                                        const float* __restrict__ es,
                                                        const float* __restrict__ ed,
                                                        const int* __restrict__ rowptr,
                                                        const int* __restrict__ csr,
                                                        const unsigned short* __restrict__ bias,
                                                        void* __restrict__ out,
                                                        int n, int ET,
                                                        const int* __restrict__ flagp) {
    constexpr int LPE = CH / 32;  // lanes per edge, 32 ch each
    constexpr int EPW = 64 / LPE; // edges in flight
    int w = blockIdx.x * 4 + (threadIdx.x >> 6); // one wave per dst node
    if (w >= n) return;
    int lane = threadIdx.x & 63;
    int eh = lane / LPE;          // edge slot
    int cl = lane % LPE;          // channel group: ch = cl*32 .. cl*32+31
    int f32out = DUAL ? flagp[0] : 0;
    int start = rowptr[w], end = rowptr[w + 1];
    start = max(0, min(start, ET));
    end = max(start, min(end, ET));
    float edv = ed[w];

    // pass 0: segment max of leaky(e_src+e_dst)
    float m = -1e30f;
    for (int j = start + lane; j < end; j += 64) {
        int s = csr[j];
        s = ((unsigned)s < (unsigned)n) ? s : 0;
        float v = es[s] + edv;
        v = (v > 0.f) ? v : 0.2f * v;
        m = fmaxf(m, v);
    }
    #pragma unroll
    for (int off = 32; off; off >>= 1) m = fmaxf(m, __shfl_xor(m, off));
    if (!(m > -1e29f)) m = 0.f;

    float ssum = 0.f;
    float acc[32];
    #pragma unroll
    for (int i = 0; i < 32; ++i) acc[i] = 0.f;

    for (int base = start; base < end; base += 64) {
        int j = base + lane;
        float p = 0.f;
        int sidx = 0;
        if (j < end) {
            int s = csr[j];
            sidx = ((unsigned)s < (unsigned)n) ? s : 0;
            float v = es[sidx] + edv;
            v = (v > 0.f) ? v : 0.2f * v;
            p = __expf(v - m);
        }
        ssum += p;
        int cnt = min(64, end - base);
        for (int g = 0; g < cnt; g += EPW) {
            int sl = g + eh;
            float pj = __shfl(p, sl);
            int sj = __shfl(sidx, sl);
            if (pj > 0.f) { // tail/pad slots have p==0: skip load & fma
                const uint4* hp = (const uint4*)(h + (size_t)sj * CH + cl * 32);
                uint4 u0 = hp[0];
                uint4 u1 = hp[1];
                uint4 u2 = hp[2];
                uint4 u3 = hp[3];
                unsigned int uw[8] = {u0.x, u0.y, u0.z, u0.w, u1.x, u1.y, u1.z, u1.w};
                #pragma unroll
                for (int i = 0; i < 8; ++i) {
                    acc[2 * i]     += pj * bf2f((unsigned short)(uw[i] & 0xffff));
                    acc[2 * i + 1] += pj * bf2f((unsigned short)(uw[i] >> 16));
                }
                unsigned int uw2[8] = {u2.x, u2.y, u2.z, u2.w, u3.x, u3.y, u3.z, u3.w};
                #pragma unroll
                for (int i = 0; i < 8; ++i) {
                    acc[16 + 2 * i]     += pj * bf2f((unsigned short)(uw2[i] & 0xffff));
                    acc[16 + 2 * i + 1] += pj * bf2f((unsigned short)(uw2[i] >> 16));
                }
            }
        }
    }
    #pragma unroll
    for (int off = 32; off; off >>= 1) ssum += __shfl_xor(ssum, off);
    // reduce across edge slots (lanes sharing cl differ by multiples of LPE)
    #pragma unroll
    for (int off = 32; off >= LPE; off >>= 1)
        #pragma unroll
        for (int i = 0; i < 32; ++i) acc[i] += __shfl_xor(acc[i], off);

    if (lane < LPE) {
        float inv = 1.f / fmaxf(ssum, 1e-20f);
        const uint4* bp = (const uint4*)(bias + cl * 32);
        #pragma unroll
        for (int half = 0; half < 2; ++half) {
            uint4 b0 = bp[half * 2], b1 = bp[half * 2 + 1];
            unsigned int bw[8] = {b0.x, b0.y, b0.z, b0.w, b1.x, b1.y, b1.z, b1.w};
            float o[16];
            #pragma unroll
            for (int i = 0; i < 8; ++i) {
                float v0 = acc[half * 16 + 2 * i] * inv + bf2f((unsigned short)(bw[i] & 0xffff));
                float v1 = acc[half * 16 + 2 * i + 1] * inv + bf2f((unsigned short)(bw[i] >> 16));
                if (RELU) { v0 = fmaxf(v0, 0.f); v1 = fmaxf(v1, 0.f); }
                o[2 * i] = fin(v0);
                o[2 * i + 1] = fin(v1);
            }
            size_t idx = (size_t)w * CH + cl * 32 + half * 16;
            if (DUAL && f32out) {
                float4* fp = (float4*)((float*)out + idx);
                #pragma unroll
                for (int q = 0; q < 4; ++q)
                    fp[q] = (float4){o[4 * q], o[4 * q + 1], o[4 * q + 2], o[4 * q + 3]};
            } else {
                uint4 pu;
                pu.x = (unsigned)f2bf(o[0]) | ((unsigned)f2bf(o[1]) << 16);
                pu.y = (unsigned)f2bf(o[2]) | ((unsigned)f2bf(o[3]) << 16);
                pu.z = (unsigned)f2bf(o[4]) | ((unsigned)f2bf(o[5]) << 16);
                pu.w = (unsigned)f2bf(o[6]) | ((unsigned)f2bf(o[7]) << 16);
                uint4 pv;
                pv.x = (unsigned)f2bf(o[8])  | ((unsigned)f2bf(o[9])  << 16);
                pv.y = (unsigned)f2bf(o[10]) | ((unsigned)f2bf(o[11]) << 16);
                pv.z = (unsigned)f2bf(o[12]) | ((unsigned)f2bf(o[13]) << 16);
                pv.w = (unsigned)f2bf(o[14]) | ((unsigned)f2bf(o[15]) << 16);
                uint4* up = (uint4*)((unsigned short*)out + idx);
                up[0] = pu;
                up[1] = pv;
            }
        }
    }
}

// ---------------- launch ----------------

extern "C" void kernel_launch(void* const* d_in, const int* in_sizes, int n_in,
                              void* d_out, int out_size, void* d_ws, size_t ws_size,
                              hipStream_t stream) {
    int gOut = (out_size + 255) / 256;
    if (n_in != 11) {
        fill_kernel<<<gOut, 256, 0, stream>>>((unsigned short*)d_out, out_size, 999.f);
        return;
    }

    const int N = in_sizes[0] / 512; // 50000
    const int E = in_sizes[1] / 2;   // 800000
    const int ET = E + N;

    const int NX  = in_sizes[0];
    const int NW1 = in_sizes[3];
    const int NA  = in_sizes[4];
    const int NB1 = in_sizes[6];
    const int NW2 = in_sizes[7];
    const int NA2 = in_sizes[8];
    const int NB2 = in_sizes[10];

    size_t off = 0;
    auto reserve = [&](size_t bytes) {
        size_t o = off;
        off = (off + bytes + 255) & ~(size_t)255;
        return o;
    };
    size_t o_flag   = reserve(256);
    size_t o_es     = reserve((size_t)N * 4);
    size_t o_ed     = reserve((size_t)N * 4);
    size_t o_deg    = reserve((size_t)N * 4);
    size_t o_rowptr = reserve((size_t)(N + 1) * 4);
    size_t o_cursor = reserve((size_t)N * 4);
    size_t o_bsum   = reserve(((size_t)N / 256 + 2) * 4);
    size_t o_csr    = reserve((size_t)ET * 4);
    size_t o_h1     = reserve((size_t)N * 256 * 2);
    size_t o_out1   = reserve((size_t)N * 256 * 2);
    size_t o_xc     = reserve((size_t)NX * 2);
    size_t o_w1c    = reserve((size_t)NW1 * 2);
    size_t o_a1s    = reserve((size_t)NA * 2);
    size_t o_a1d    = reserve((size_t)NA * 2);
    size_t o_b1c    = reserve((size_t)NB1 * 2);
    size_t o_w2c    = reserve((size_t)NW2 * 2);
    size_t o_a2s    = reserve((size_t)NA2 * 2);
    size_t o_a2d    = reserve((size_t)NA2 * 2);
    size_t o_b2c    = reserve((size_t)NB2 * 2);
    size_t need = off;

    char* base = nullptr;
    if (ws_size >= need) base = (char*)d_ws;
    else if (g_scratch && SCRATCH_BYTES >= need) base = (char*)g_scratch;
    if (!base) {
        fill_kernel<<<gOut, 256, 0, stream>>>((unsigned short*)d_out, out_size,
                                              100.f + (float)(ws_size >> 20));
        return;
    }

    int*   flag    = (int*)(base + o_flag);
    float* es      = (float*)(base + o_es);
    float* ed      = (float*)(base + o_ed);
    int*   deg     = (int*)(base + o_deg);
    int*   rowptr  = (int*)(base + o_rowptr);
    int*   cursor  = (int*)(base + o_cursor);
    int*   bsum    = (int*)(base + o_bsum);
    int*   csr     = (int*)(base + o_csr);
    unsigned short* h1   = (unsigned short*)(base + o_h1);
    unsigned short* out1 = (unsigned short*)(base + o_out1);
    unsigned short* xc   = (unsigned short*)(base + o_xc);
    unsigned short* w1c  = (unsigned short*)(base + o_w1c);
    unsigned short* a1sc = (unsigned short*)(base + o_a1s);
    unsigned short* a1dc = (unsigned short*)(base + o_a1d);
    unsigned short* b1c  = (unsigned short*)(base + o_b1c);
    unsigned short* w2c  = (unsigned short*)(base + o_w2c);
    unsigned short* a2sc = (unsigned short*)(base + o_a2s);
    unsigned short* a2dc = (unsigned short*)(base + o_a2d);
    unsigned short* b2c  = (unsigned short*)(base + o_b2c);

    const int* ei = (const int*)d_in[1];

    probe_kernel<<<1, 64, 0, stream>>>((const unsigned int*)d_in[0], flag);
    cvtx_kernel<<<(NX / 4 + 255) / 256, 256, 0, stream>>>(d_in[0], xc, NX / 4, flag);
    CvtBatch cb;
    cb.src[0] = d_in[3];  cb.dst[0] = w1c;  cb.n[0] = NW1;
    cb.src[1] = d_in[4];  cb.dst[1] = a1sc; cb.n[1] = NA;
    cb.src[2] = d_in[5];  cb.dst[2] = a1dc; cb.n[2] = NA;
    cb.src[3] = d_in[6];  cb.dst[3] = b1c;  cb.n[3] = NB1;
    cb.src[4] = d_in[7];  cb.dst[4] = w2c;  cb.n[4] = NW2;
    cb.src[5] = d_in[8];  cb.dst[5] = a2sc; cb.n[5] = NA2;
    cb.src[6] = d_in[9];  cb.dst[6] = a2dc; cb.n[6] = NA2;
    cb.src[7] = d_in[10]; cb.dst[7] = b2c;  cb.n[7] = NB2;
    int totalSmall = NW1 + NA + NA + NB1 + NW2 + NA2 + NA2 + NB2;
    cvt_batch_kernel<<<(totalSmall + 255) / 256, 256, 0, stream>>>(cb, flag);

    // CSR build (csr memset dropped: scatter provably fills every slot)
    hipMemsetAsync(deg, 0, (size_t)N * 4, stream);
    int gE = (ET + 255) / 256;
    int gN256 = (N + 255) / 256;
    deg_kernel<<<gE, 256, 0, stream>>>(ei, E, N, deg);
    scan_bsum_kernel<<<gN256, 256, 0, stream>>>(deg, bsum, N);
    scan_scan_kernel<<<1, 256, 0, stream>>>(bsum, gN256, rowptr + N);
    scan_write_kernel<<<gN256, 256, 0, stream>>>(deg, bsum, rowptr, cursor, N);
    scatter_kernel<<<gE, 256, 0, stream>>>(ei, E, N, cursor, csr);

    int numM = (N + 127) / 128;
    int gNode = (N + 3) / 4;

    // layer 1
    gemm_tile_kernel<512, 2><<<numM * 2, 256, 0, stream>>>(xc, w1c, h1, N);
    escore_kernel<4><<<gNode, 256, 0, stream>>>(h1, a1sc, a1dc, es, ed, N);
    aggregate_kernel<256, true, false><<<gNode, 256, 0, stream>>>(h1, es, ed, rowptr, csr, b1c,
                                                                  out1, N, ET, flag);
    // layer 2 (h2 reuses h1 buffer)
    unsigned short* h2 = h1;
    gemm_tile_kernel<256, 1><<<numM, 256, 0, stream>>>(out1, w2c, h2, N);
    escore_kernel<2><<<gNode, 256, 0, stream>>>(h2, a2sc, a2dc, es, ed, N);
    aggregate_kernel<128, false, true><<<gNode, 256, 0, stream>>>(h2, es, ed, rowptr, csr, b2c,
                                                                  d_out, N, ET, flag);
}